// Round 2
// baseline (114.266 us; speedup 1.0000x reference)
//
#include <hip/hip_runtime.h>
#include <math.h>

struct V2 { float x, y; };

// Select H[idx] from a compile-time-indexed register array (no scratch).
__device__ __forceinline__ V2 dynsel8(const V2* H, int idx) {
    V2 r = H[0];
#pragma unroll
    for (int k = 1; k < 8; k++) {
        if (idx == k) r = H[k];
    }
    return r;
}

// atan2 ordering class: (-pi,0) < {0} < (0,pi) < {pi}
__device__ __forceinline__ int ang_class(float x, float y) {
    if (y < 0.f) return 0;
    if (y > 0.f) return 2;
    return (x >= 0.f) ? 1 : 3;
}

// Compare angle(a) vs angle(b) exactly (matches true atan2 ordering).
// Returns -1 if ang(a)<ang(b), 0 if equal, +1 if greater.
__device__ __forceinline__ int ang_cmp(V2 a, V2 b) {
    int ca = ang_class(a.x, a.y);
    int cb = ang_class(b.x, b.y);
    if (ca != cb) return (ca < cb) ? -1 : 1;
    if (ca == 0 || ca == 2) {
        // both strictly inside an open half-plane of width pi:
        // cross sign gives exact ordering. float32 -> double products are exact.
        double cr = (double)a.x * (double)b.y - (double)a.y * (double)b.x;
        if (cr > 0.0) return -1;
        if (cr < 0.0) return 1;
    }
    return 0;
}

// Stable ascending sort of 4 points by angle around centroid (exact ordering).
__device__ __forceinline__ void angle_sort4(float4 lo, float4 hi, V2 out[4]) {
    V2 p[4];
    p[0].x = lo.x; p[0].y = lo.y;
    p[1].x = lo.z; p[1].y = lo.w;
    p[2].x = hi.x; p[2].y = hi.y;
    p[3].x = hi.z; p[3].y = hi.w;
    // match XLA's sequential mean reduction rounding
    float cx = (((p[0].x + p[1].x) + p[2].x) + p[3].x) * 0.25f;
    float cy = (((p[0].y + p[1].y) + p[2].y) + p[3].y) * 0.25f;
    V2 r[4];
#pragma unroll
    for (int i = 0; i < 4; i++) { r[i].x = p[i].x - cx; r[i].y = p[i].y - cy; }
    int rank[4];
#pragma unroll
    for (int i = 0; i < 4; i++) {
        int rk = 0;
#pragma unroll
        for (int j = 0; j < 4; j++) {
            if (j == i) continue;
            int c = ang_cmp(r[j], r[i]);
            if (c < 0 || (c == 0 && j < i)) rk++;   // stable argsort
        }
        rank[i] = rk;
    }
#pragma unroll
    for (int k = 0; k < 4; k++) {
#pragma unroll
        for (int i = 0; i < 4; i++) {
            if (rank[i] == k) out[k] = p[i];
        }
    }
}

// next-vertex fetch replicating  poly[(idx+1) % max(nv,1)]  with JAX clamping
// (index 8 clamps to 7 when nv > 8). idx is a compile-time constant.
__device__ __forceinline__ V2 next_vertex(const V2* poly, int idx, int nv) {
    if (idx == 7) return (nv == 8) ? poly[0] : poly[7];     // nv>8 -> clamp to self
    return ((idx + 1) == nv) ? poly[0] : poly[idx + 1];
}

__global__ __launch_bounds__(256) void poly_iou_kernel(
    const float* __restrict__ preds, const float* __restrict__ targets,
    float* __restrict__ out, int n)
{
    int gid = blockIdx.x * blockDim.x + threadIdx.x;
    if (gid >= n) return;

    const float4* p4 = reinterpret_cast<const float4*>(preds);
    const float4* t4 = reinterpret_cast<const float4*>(targets);
    float4 a0 = p4[2 * gid], a1 = p4[2 * gid + 1];
    float4 b0 = t4[2 * gid], b1 = t4[2 * gid + 1];

    V2 P[4], T[4];
    angle_sort4(a0, a1, P);
    angle_sort4(b0, b1, T);

    // ---- Sutherland-Hodgman intersection: subject P clipped by edges of T ----
    V2 poly[8];
    int nv = 4;
#pragma unroll
    for (int k = 0; k < 4; k++) poly[k] = P[k];
#pragma unroll
    for (int k = 4; k < 8; k++) { poly[k].x = 0.f; poly[k].y = 0.f; }

#pragma unroll
    for (int e = 0; e < 4; e++) {
        V2 A = T[e];
        V2 B = T[(e + 1) & 3];
        float ex = B.x - A.x, ey = B.y - A.y;
        V2 npoly[8];
#pragma unroll
        for (int s = 0; s < 8; s++) { npoly[s].x = 0.f; npoly[s].y = 0.f; }
        int cnt = 0;
#pragma unroll
        for (int idx = 0; idx < 8; idx++) {
            bool active = (idx < nv);
            V2 cur = poly[idx];
            V2 nxt = next_vertex(poly, idx, nv);
            float d_cur = ex * (cur.y - A.y) - ey * (cur.x - A.x);
            float d_nxt = ex * (nxt.y - A.y) - ey * (nxt.x - A.x);
            bool in_cur = (d_cur >= 0.f);
            bool in_nxt = (d_nxt >= 0.f);
            float den = d_cur - d_nxt;
            den = (fabsf(den) < 1e-12f) ? 1e-12f : den;
            float t = d_cur / den;
            V2 ipt;
            ipt.x = cur.x + t * (nxt.x - cur.x);
            ipt.y = cur.y + t * (nxt.y - cur.y);
            bool v0 = active && in_cur;
            bool v1 = active && (in_cur != in_nxt);
            // compaction: emit cur (if v0) then ipt (if v1), interleaved order
#pragma unroll
            for (int s = 0; s < 8; s++) {
                if (v0 && cnt == s) npoly[s] = cur;
            }
            cnt += v0 ? 1 : 0;
#pragma unroll
            for (int s = 0; s < 8; s++) {
                if (v1 && cnt == s) npoly[s] = ipt;
            }
            cnt += v1 ? 1 : 0;
        }
#pragma unroll
        for (int s = 0; s < 8; s++) poly[s] = npoly[s];
        nv = cnt;   // reference keeps unclamped count
    }

    float inter = 0.f;
#pragma unroll
    for (int idx = 0; idx < 8; idx++) {
        bool active = (idx < nv);
        V2 cur = poly[idx];
        V2 nxt = next_vertex(poly, idx, nv);
        float term = cur.x * nxt.y - nxt.x * cur.y;
        inter += active ? term : 0.f;
    }
    inter = 0.5f * fabsf(inter);

    // ---- convex hull (gift wrapping) of the 8 sorted points ----
    V2 H[8];
#pragma unroll
    for (int k = 0; k < 4; k++) { H[k] = P[k]; H[4 + k] = T[k]; }

    int start = 0;
    float miny = H[0].y;
#pragma unroll
    for (int k = 1; k < 8; k++) {
        if (H[k].y < miny) { miny = H[k].y; start = k; }  // first min (strict <)
    }

    V2 vstart = dynsel8(H, start);
    V2 prev = vstart;
    int cur = start;
    bool done = false;
    float harea = 0.f;

#pragma unroll 1
    for (int s = 0; s < 8; s++) {
        V2 pc = dynsel8(H, cur);
        V2 rel[8];
        float d2[8];
#pragma unroll
        for (int k = 0; k < 8; k++) {
            rel[k].x = H[k].x - pc.x;
            rel[k].y = H[k].y - pc.y;
            d2[k] = rel[k].x * rel[k].x + rel[k].y * rel[k].y;
        }
        int best = 0;
        float bestscore = -2.f;
#pragma unroll
        for (int k = 0; k < 8; k++) {
            bool ok = (d2[k] > 1e-12f);
#pragma unroll
            for (int j = 0; j < 8; j++) {
                float c = rel[k].x * rel[j].y - rel[k].y * rel[j].x;
                ok = ok && (c >= -1e-6f);
            }
            float score = ok ? d2[k] : -1.f;
            if (score > bestscore) { bestscore = score; best = k; }  // first max
        }
        int nxt = done ? cur : best;
        done = done || (nxt == start);
        V2 pv = dynsel8(H, nxt);
        harea += prev.x * pv.y - pv.x * prev.y;
        prev = pv;
        cur = nxt;
        if (__all(done)) break;   // wave-uniform early exit; skipped steps add exact 0
    }
    harea += prev.x * vstart.y - vstart.x * prev.y;
    harea = 0.5f * fabsf(harea);

    float iou = (harea > 1e-12f) ? (inter / fmaxf(harea, 1e-12f)) : 0.f;
    out[gid] = 1.f - iou;
}

extern "C" void kernel_launch(void* const* d_in, const int* in_sizes, int n_in,
                              void* d_out, int out_size, void* d_ws, size_t ws_size,
                              hipStream_t stream) {
    const float* preds = (const float*)d_in[0];
    const float* targets = (const float*)d_in[1];
    float* out = (float*)d_out;
    int n = in_sizes[0] / 8;
    int block = 256;
    int grid = (n + block - 1) / block;
    hipLaunchKernelGGL(poly_iou_kernel, dim3(grid), dim3(block), 0, stream,
                       preds, targets, out, n);
}

// Round 3
// 42.919 us; speedup vs baseline: 2.6624x; 2.6624x over previous
//
#include <hip/hip_runtime.h>
#include <math.h>

struct V2 { float x, y; };

#define NT 256

// ---- exact atan2-ordering comparator (verified absmax 0 in round 2) ----
__device__ __forceinline__ int ang_class(float x, float y) {
    if (y < 0.f) return 0;
    if (y > 0.f) return 2;
    return (x >= 0.f) ? 1 : 3;
}

__device__ __forceinline__ int ang_cmp(V2 a, V2 b) {
    int ca = ang_class(a.x, a.y);
    int cb = ang_class(b.x, b.y);
    if (ca != cb) return (ca < cb) ? -1 : 1;
    if (ca == 0 || ca == 2) {
        // float32 -> double products are exact: true atan2 ordering
        double cr = (double)a.x * (double)b.y - (double)a.y * (double)b.x;
        if (cr > 0.0) return -1;
        if (cr < 0.0) return 1;
    }
    return 0;
}

__device__ __forceinline__ void angle_sort4(float4 lo, float4 hi, V2 out[4]) {
    V2 p[4];
    p[0].x = lo.x; p[0].y = lo.y;
    p[1].x = lo.z; p[1].y = lo.w;
    p[2].x = hi.x; p[2].y = hi.y;
    p[3].x = hi.z; p[3].y = hi.w;
    float cx = (((p[0].x + p[1].x) + p[2].x) + p[3].x) * 0.25f;
    float cy = (((p[0].y + p[1].y) + p[2].y) + p[3].y) * 0.25f;
    V2 r[4];
#pragma unroll
    for (int i = 0; i < 4; i++) { r[i].x = p[i].x - cx; r[i].y = p[i].y - cy; }
    int rank[4];
#pragma unroll
    for (int i = 0; i < 4; i++) {
        int rk = 0;
#pragma unroll
        for (int j = 0; j < 4; j++) {
            if (j == i) continue;
            int c = ang_cmp(r[j], r[i]);
            if (c < 0 || (c == 0 && j < i)) rk++;   // stable argsort
        }
        rank[i] = rk;
    }
#pragma unroll
    for (int k = 0; k < 4; k++) {
#pragma unroll
        for (int i = 0; i < 4; i++) {
            if (rank[i] == k) out[k] = p[i];
        }
    }
}

// One Sutherland-Hodgman round: read 8 slots from `in_`, clip by edge A->B,
// compact into `out_` via dynamic LDS writes. Returns new (unclamped) count.
__device__ __forceinline__ int clip_round(const float2 (*in_)[NT], float2 (*out_)[NT],
                                          V2 A, V2 B, int nv, int tid)
{
    float ex = B.x - A.x, ey = B.y - A.y;
    V2 p[8]; float d[8];
#pragma unroll
    for (int s = 0; s < 8; s++) {
        float2 v = in_[s][tid];
        p[s].x = v.x; p[s].y = v.y;
        d[s] = ex * (v.y - A.y) - ey * (v.x - A.x);
    }
    int cnt = 0;
#pragma unroll
    for (int idx = 0; idx < 8; idx++) {
        // next vertex: replicates poly[(idx+1) % max(nv,1)] with JAX index-clamp
        V2 nx; float dn;
        if (idx == 7) {
            bool w = (nv == 8);
            nx.x = w ? p[0].x : p[7].x;
            nx.y = w ? p[0].y : p[7].y;
            dn   = w ? d[0]   : d[7];
        } else {
            bool w = ((idx + 1) == nv);
            nx.x = w ? p[0].x : p[idx + 1].x;
            nx.y = w ? p[0].y : p[idx + 1].y;
            dn   = w ? d[0]   : d[idx + 1];
        }
        bool active = idx < nv;
        bool in_cur = d[idx] >= 0.f;
        bool in_nxt = dn >= 0.f;
        float den = d[idx] - dn;
        den = (fabsf(den) < 1e-12f) ? 1e-12f : den;
        float t = __fdividef(d[idx], den);
        float ix = p[idx].x + t * (nx.x - p[idx].x);
        float iy = p[idx].y + t * (nx.y - p[idx].y);
        bool v0 = active && in_cur;
        bool v1 = active && (in_cur != in_nxt);
        if (v0 && cnt < 8) out_[cnt][tid] = make_float2(p[idx].x, p[idx].y);
        cnt += v0 ? 1 : 0;
        if (v1 && cnt < 8) out_[cnt][tid] = make_float2(ix, iy);
        cnt += v1 ? 1 : 0;
    }
    return cnt;
}

__global__ __launch_bounds__(256) void poly_iou_kernel(
    const float* __restrict__ preds, const float* __restrict__ targets,
    float* __restrict__ out, int n)
{
    __shared__ float2 bufA[8][NT];
    __shared__ float2 bufB[8][NT];
    int tid = threadIdx.x;
    int gid = blockIdx.x * NT + tid;
    if (gid >= n) return;

    const float4* p4 = reinterpret_cast<const float4*>(preds);
    const float4* t4 = reinterpret_cast<const float4*>(targets);
    float4 a0 = p4[2 * gid], a1 = p4[2 * gid + 1];
    float4 b0 = t4[2 * gid], b1 = t4[2 * gid + 1];

    V2 P[4], T[4];
    angle_sort4(a0, a1, P);
    angle_sort4(b0, b1, T);

    // ---- edge 0 (nv=4 compile-time): registers -> bufA ----
    int nv;
    {
        float ex = T[1].x - T[0].x, ey = T[1].y - T[0].y;
        float dd[4];
#pragma unroll
        for (int k = 0; k < 4; k++)
            dd[k] = ex * (P[k].y - T[0].y) - ey * (P[k].x - T[0].x);
        int cnt = 0;
#pragma unroll
        for (int idx = 0; idx < 4; idx++) {
            int j = (idx + 1) & 3;
            bool in_cur = dd[idx] >= 0.f;
            bool in_nxt = dd[j] >= 0.f;
            float den = dd[idx] - dd[j];
            den = (fabsf(den) < 1e-12f) ? 1e-12f : den;
            float t = __fdividef(dd[idx], den);
            float ix = P[idx].x + t * (P[j].x - P[idx].x);
            float iy = P[idx].y + t * (P[j].y - P[idx].y);
            bool v1 = (in_cur != in_nxt);
            if (in_cur) bufA[cnt][tid] = make_float2(P[idx].x, P[idx].y);
            cnt += in_cur ? 1 : 0;
            if (v1) bufA[cnt][tid] = make_float2(ix, iy);
            cnt += v1 ? 1 : 0;
        }
        nv = cnt;
    }

    // ---- edges 1..3, ping-pong A->B->A->B ----
    nv = clip_round(bufA, bufB, T[1], T[2], nv, tid);
    nv = clip_round(bufB, bufA, T[2], T[3], nv, tid);
    nv = clip_round(bufA, bufB, T[3], T[0], nv, tid);

    // ---- shoelace of final polygon (bufB) ----
    float inter = 0.f;
    {
        V2 q[8];
#pragma unroll
        for (int s = 0; s < 8; s++) {
            float2 v = bufB[s][tid];
            q[s].x = v.x; q[s].y = v.y;
        }
#pragma unroll
        for (int idx = 0; idx < 8; idx++) {
            V2 nx;
            if (idx == 7) {
                bool w = (nv == 8);
                nx.x = w ? q[0].x : q[7].x;
                nx.y = w ? q[0].y : q[7].y;
            } else {
                bool w = ((idx + 1) == nv);
                nx.x = w ? q[0].x : q[idx + 1].x;
                nx.y = w ? q[0].y : q[idx + 1].y;
            }
            bool active = idx < nv;
            float term = q[idx].x * nx.y - nx.x * q[idx].y;
            inter += active ? term : 0.f;
        }
        inter = 0.5f * fabsf(inter);
    }

    // ---- convex hull (gift wrap, O(n) per step) of the 8 sorted points ----
    V2 h[8];
#pragma unroll
    for (int k = 0; k < 4; k++) { h[k] = P[k]; h[4 + k] = T[k]; }

    int start = 0; V2 vs = h[0];
#pragma unroll
    for (int k = 1; k < 8; k++) {           // first-index argmin of y
        bool b = h[k].y < vs.y;
        start = b ? k : start;
        vs.x  = b ? h[k].x : vs.x;
        vs.y  = b ? h[k].y : vs.y;
    }

    V2 pc = vs; int cur = start; bool done = false; float harea = 0.f;
#pragma unroll 1
    for (int s = 0; s < 8; s++) {
        // most-clockwise ray from pc; farthest on collinear; first index on tie
        int best = -1; float bx = 0.f, by = 0.f, bd = 0.f, px = 0.f, py = 0.f;
#pragma unroll
        for (int k = 0; k < 8; k++) {
            float rx = h[k].x - pc.x, ry = h[k].y - pc.y;
            float d2 = rx * rx + ry * ry;
            bool ok = d2 > 1e-12f;
            float c = bx * ry - by * rx;    // cross(best, k)
            bool take = ok && ((best < 0) || (c < 0.f) || ((c == 0.f) && (d2 > bd)));
            best = take ? k : best;
            bx = take ? rx : bx; by = take ? ry : by; bd = take ? d2 : bd;
            px = take ? h[k].x : px; py = take ? h[k].y : py;
        }
        bool stay = done || (best < 0);
        int nxt = stay ? cur : best;
        V2 pv;
        pv.x = stay ? pc.x : px;
        pv.y = stay ? pc.y : py;
        harea += pc.x * pv.y - pv.x * pc.y;
        done = done || (nxt == start);
        pc = pv; cur = nxt;
        if (__all(done)) break;             // skipped steps contribute exact 0
    }
    harea += pc.x * vs.y - vs.x * pc.y;     // closure
    harea = 0.5f * fabsf(harea);

    float iou = (harea > 1e-12f) ? (inter / fmaxf(harea, 1e-12f)) : 0.f;
    out[gid] = 1.f - iou;
}

extern "C" void kernel_launch(void* const* d_in, const int* in_sizes, int n_in,
                              void* d_out, int out_size, void* d_ws, size_t ws_size,
                              hipStream_t stream) {
    const float* preds = (const float*)d_in[0];
    const float* targets = (const float*)d_in[1];
    float* out = (float*)d_out;
    int n = in_sizes[0] / 8;
    int block = NT;
    int grid = (n + block - 1) / block;
    hipLaunchKernelGGL(poly_iou_kernel, dim3(grid), dim3(block), 0, stream,
                       preds, targets, out, n);
}

// Round 4
// 32.287 us; speedup vs baseline: 3.5390x; 1.3293x over previous
//
#include <hip/hip_runtime.h>
#include <math.h>

struct V2 { float x, y; };

#define NT 256

// angle class matching atan2 range ordering: 0: y<0 (-pi,0); 1: y==0,x>=0 {0};
// 2: y>0 (0,pi); 3: y==0,x<0 {pi}
__device__ __forceinline__ int ang_class(float x, float y) {
    return (y < 0.f) ? 0 : ((y > 0.f) ? 2 : ((x >= 0.f) ? 1 : 3));
}

// Stable ascending argsort of 4 points by exact atan2 ordering around centroid.
// 6 pairwise comparisons; double products of float32 are exact.
__device__ __forceinline__ void angle_sort4(float4 lo, float4 hi, V2 out[4]) {
    V2 p[4];
    p[0].x = lo.x; p[0].y = lo.y;
    p[1].x = lo.z; p[1].y = lo.w;
    p[2].x = hi.x; p[2].y = hi.y;
    p[3].x = hi.z; p[3].y = hi.w;
    float cx = (((p[0].x + p[1].x) + p[2].x) + p[3].x) * 0.25f;
    float cy = (((p[0].y + p[1].y) + p[2].y) + p[3].y) * 0.25f;
    float rx[4], ry[4]; int cls[4];
#pragma unroll
    for (int i = 0; i < 4; i++) {
        rx[i] = p[i].x - cx; ry[i] = p[i].y - cy;
        cls[i] = ang_class(rx[i], ry[i]);
    }
    int rank[4] = {0, 0, 0, 0};
#pragma unroll
    for (int i = 0; i < 4; i++) {
#pragma unroll
        for (int j = i + 1; j < 4; j++) {
            int cd = cls[i] - cls[j];
            // cr > 0 -> ang_i < ang_j ; cr == 0 for the y==0 classes (exact)
            double cr = (double)rx[i] * (double)ry[j] - (double)ry[i] * (double)rx[j];
            bool gt = (cd > 0) || (cd == 0 && cr < 0.0);  // ang_i > ang_j
            rank[i] += gt ? 1 : 0;
            rank[j] += gt ? 0 : 1;   // includes equal-angle stable tie (i<j)
        }
    }
#pragma unroll
    for (int k = 0; k < 4; k++) {
#pragma unroll
        for (int i = 0; i < 4; i++) {
            if (rank[i] == k) out[k] = p[i];
        }
    }
}

// One Sutherland-Hodgman round, IN-PLACE: reads all 8 slots of this thread's
// column into registers, clips by edge A->B, compacts back into same column.
__device__ __forceinline__ int clip_round(float2 (*buf)[NT], V2 A, V2 B,
                                          int nv, int tid)
{
    float ex = B.x - A.x, ey = B.y - A.y;
    V2 p[8]; float d[8];
#pragma unroll
    for (int s = 0; s < 8; s++) {
        float2 v = buf[s][tid];
        p[s].x = v.x; p[s].y = v.y;
        d[s] = ex * (v.y - A.y) - ey * (v.x - A.x);
    }
    int cnt = 0;
#pragma unroll
    for (int idx = 0; idx < 8; idx++) {
        // next vertex: replicates poly[(idx+1) % max(nv,1)] with JAX index-clamp
        V2 nx; float dn;
        if (idx == 7) {
            bool w = (nv == 8);          // nv>8 -> index 8 clamps to slot 7 (self)
            nx.x = w ? p[0].x : p[7].x;
            nx.y = w ? p[0].y : p[7].y;
            dn   = w ? d[0]   : d[7];
        } else {
            bool w = ((idx + 1) == nv);
            nx.x = w ? p[0].x : p[idx + 1].x;
            nx.y = w ? p[0].y : p[idx + 1].y;
            dn   = w ? d[0]   : d[idx + 1];
        }
        bool active = idx < nv;
        bool in_cur = d[idx] >= 0.f;
        bool in_nxt = dn >= 0.f;
        float den = d[idx] - dn;
        den = (fabsf(den) < 1e-12f) ? 1e-12f : den;
        float t = __fdividef(d[idx], den);
        float ix = p[idx].x + t * (nx.x - p[idx].x);
        float iy = p[idx].y + t * (nx.y - p[idx].y);
        bool v0 = active && in_cur;
        bool v1 = active && (in_cur != in_nxt);
        if (v0 && cnt < 8) buf[cnt][tid] = make_float2(p[idx].x, p[idx].y);
        cnt += v0 ? 1 : 0;
        if (v1 && cnt < 8) buf[cnt][tid] = make_float2(ix, iy);
        cnt += v1 ? 1 : 0;
    }
    return cnt;   // unclamped count, like the reference
}

__global__ __launch_bounds__(256, 8) void poly_iou_kernel(
    const float* __restrict__ preds, const float* __restrict__ targets,
    float* __restrict__ out, int n)
{
    __shared__ float2 buf[8][NT];   // 16 KB: per-thread 8-slot scratch column
    int tid = threadIdx.x;
    int gid = blockIdx.x * NT + tid;
    if (gid >= n) return;

    const float4* p4 = reinterpret_cast<const float4*>(preds);
    const float4* t4 = reinterpret_cast<const float4*>(targets);
    float4 a0 = p4[2 * gid], a1 = p4[2 * gid + 1];
    float4 b0 = t4[2 * gid], b1 = t4[2 * gid + 1];

    V2 P[4], T[4];
    angle_sort4(a0, a1, P);
    angle_sort4(b0, b1, T);

    // ---- edge 0 (nv=4 compile-time): registers -> buf ----
    int nv;
    {
        float ex = T[1].x - T[0].x, ey = T[1].y - T[0].y;
        float dd[4];
#pragma unroll
        for (int k = 0; k < 4; k++)
            dd[k] = ex * (P[k].y - T[0].y) - ey * (P[k].x - T[0].x);
        int cnt = 0;
#pragma unroll
        for (int idx = 0; idx < 4; idx++) {
            int j = (idx + 1) & 3;
            bool in_cur = dd[idx] >= 0.f;
            bool in_nxt = dd[j] >= 0.f;
            float den = dd[idx] - dd[j];
            den = (fabsf(den) < 1e-12f) ? 1e-12f : den;
            float t = __fdividef(dd[idx], den);
            float ix = P[idx].x + t * (P[j].x - P[idx].x);
            float iy = P[idx].y + t * (P[j].y - P[idx].y);
            bool v1 = (in_cur != in_nxt);
            if (in_cur) buf[cnt][tid] = make_float2(P[idx].x, P[idx].y);
            cnt += in_cur ? 1 : 0;
            if (v1) buf[cnt][tid] = make_float2(ix, iy);
            cnt += v1 ? 1 : 0;
        }
        nv = cnt;   // max 8 from 4 vertices, no drop possible
    }

    // ---- edges 1..3, in place ----
    nv = clip_round(buf, T[1], T[2], nv, tid);
    nv = clip_round(buf, T[2], T[3], nv, tid);
    nv = clip_round(buf, T[3], T[0], nv, tid);

    // ---- shoelace of final polygon ----
    float inter = 0.f;
    {
        V2 q[8];
#pragma unroll
        for (int s = 0; s < 8; s++) {
            float2 v = buf[s][tid];
            q[s].x = v.x; q[s].y = v.y;
        }
#pragma unroll
        for (int idx = 0; idx < 8; idx++) {
            V2 nx;
            if (idx == 7) {
                bool w = (nv == 8);
                nx.x = w ? q[0].x : q[7].x;
                nx.y = w ? q[0].y : q[7].y;
            } else {
                bool w = ((idx + 1) == nv);
                nx.x = w ? q[0].x : q[idx + 1].x;
                nx.y = w ? q[0].y : q[idx + 1].y;
            }
            bool active = idx < nv;
            float term = q[idx].x * nx.y - nx.x * q[idx].y;
            inter += active ? term : 0.f;
        }
        inter = 0.5f * fabsf(inter);
    }

    // ---- convex hull (gift wrap, O(n) per step) of the 8 sorted points ----
    V2 h[8];
#pragma unroll
    for (int k = 0; k < 4; k++) { h[k] = P[k]; h[4 + k] = T[k]; }

    int start = 0; V2 vs = h[0];
#pragma unroll
    for (int k = 1; k < 8; k++) {           // first-index argmin of y
        bool b = h[k].y < vs.y;
        start = b ? k : start;
        vs.x  = b ? h[k].x : vs.x;
        vs.y  = b ? h[k].y : vs.y;
    }

    V2 pc = vs; int cur = start; bool done = false; float harea = 0.f;
#pragma unroll 1
    for (int s = 0; s < 8; s++) {
        // most-clockwise ray from pc; farthest on collinear; first index on tie
        int best = -1; float bx = 0.f, by = 0.f, bd = 0.f, px = 0.f, py = 0.f;
#pragma unroll
        for (int k = 0; k < 8; k++) {
            float rx = h[k].x - pc.x, ry = h[k].y - pc.y;
            float d2 = rx * rx + ry * ry;
            bool ok = d2 > 1e-12f;
            float c = bx * ry - by * rx;    // cross(best, k)
            bool take = ok && ((best < 0) || (c < 0.f) || ((c == 0.f) && (d2 > bd)));
            best = take ? k : best;
            bx = take ? rx : bx; by = take ? ry : by; bd = take ? d2 : bd;
            px = take ? h[k].x : px; py = take ? h[k].y : py;
        }
        bool stay = done || (best < 0);
        int nxt = stay ? cur : best;
        V2 pv;
        pv.x = stay ? pc.x : px;
        pv.y = stay ? pc.y : py;
        harea += pc.x * pv.y - pv.x * pc.y;
        done = done || (nxt == start);
        pc = pv; cur = nxt;
        if (__all(done)) break;             // skipped steps contribute exact 0
    }
    harea += pc.x * vs.y - vs.x * pc.y;     // closure
    harea = 0.5f * fabsf(harea);

    float iou = (harea > 1e-12f) ? (inter / fmaxf(harea, 1e-12f)) : 0.f;
    out[gid] = 1.f - iou;
}

extern "C" void kernel_launch(void* const* d_in, const int* in_sizes, int n_in,
                              void* d_out, int out_size, void* d_ws, size_t ws_size,
                              hipStream_t stream) {
    const float* preds = (const float*)d_in[0];
    const float* targets = (const float*)d_in[1];
    float* out = (float*)d_out;
    int n = in_sizes[0] / 8;
    int block = NT;
    int grid = (n + block - 1) / block;
    hipLaunchKernelGGL(poly_iou_kernel, dim3(grid), dim3(block), 0, stream,
                       preds, targets, out, n);
}